// Round 1
// 103.157 us; speedup vs baseline: 1.0242x; 1.0242x over previous
//
#include <hip/hip_runtime.h>

// Problem constants (from reference setup_inputs)
#define BB 64
#define NN 128
#define DD 128
#define AA 1000
#define KPAD 1024
#define NEG_INF (-9.0e15f)

typedef __attribute__((ext_vector_type(8))) short short8;   // 8 bf16 MFMA frag
typedef __attribute__((ext_vector_type(4))) float floatx4;  // MFMA C/D frag
typedef __attribute__((ext_vector_type(4))) unsigned int uintx4;
typedef __attribute__((ext_vector_type(2))) unsigned int uintx2;

__device__ __forceinline__ float bflo(unsigned int u) { return __uint_as_float(u << 16); }
__device__ __forceinline__ float bfhi(unsigned int u) { return __uint_as_float(u & 0xffff0000u); }
// truncating fp32->bf16 pack (cheap; ~2^-9 rel bias, fine vs threshold)
__device__ __forceinline__ unsigned int packbf(float f0, float f1) {
  return (__float_as_uint(f0) >> 16) | (__float_as_uint(f1) & 0xffff0000u);
}
// round-to-nearest-even fp32->bf16
__device__ __forceinline__ unsigned short bf_rne(float f) {
  unsigned int u = __float_as_uint(f);
  return (unsigned short)((u + 0x7fffu + ((u >> 16) & 1u)) >> 16);
}
__device__ __forceinline__ unsigned int packbf_rne(float f0, float f1) {
  return (unsigned int)bf_rne(f0) | ((unsigned int)bf_rne(f1) << 16);
}
__device__ __forceinline__ short8 u2s(uintx4 v) {
  union { uintx4 u; short8 s; } x; x.u = v; return x.s;
}

// ---------------------------------------------------------------------------
// Prep (96 blocks x 256): blocks 0..63 -> HTg[b][d][i] = bf16(h[b]^T);
// blocks 64..95 -> ET[c][k] = bf16(emb[k][c]) via coalesced row loads + LDS
// transpose (replaces the old stride-512B global gather), k zero-padded
// to 1024. hsf is reused by both branches (66 KB -> 2 blocks/CU).
// ---------------------------------------------------------------------------
__global__ __launch_bounds__(256) void prep_kernel(
    const float* __restrict__ hidden, const float* __restrict__ emb,
    unsigned short* __restrict__ ET, unsigned short* __restrict__ HTg)
{
  __shared__ float hsf[NN * 129];
  const int t = threadIdx.x;
  const int bid = blockIdx.x;
  if (bid < BB) {
    const float* hb = hidden + (size_t)bid * NN * DD;
    #pragma unroll
    for (int u = 0; u < 16; ++u) {
      int e = u * 1024 + t * 4;
      float4 v = *reinterpret_cast<const float4*>(hb + e);
      int r = e >> 7, c = e & 127;
      float* d = &hsf[r * 129 + c];
      d[0] = v.x; d[1] = v.y; d[2] = v.z; d[3] = v.w;
    }
    __syncthreads();
    unsigned short* ht16 = HTg + (size_t)bid * NN * DD;
    #pragma unroll
    for (int u = 0; u < 8; ++u) {  // transpose via LDS columns
      int e = u * 2048 + t * 8;
      int dI = e >> 7, il = e & 127;
      float x[8];
      #pragma unroll
      for (int j = 0; j < 8; ++j) x[j] = hsf[(il + j) * 129 + dI];
      uintx4 o;
      o.x = packbf_rne(x[0], x[1]); o.y = packbf_rne(x[2], x[3]);
      o.z = packbf_rne(x[4], x[5]); o.w = packbf_rne(x[6], x[7]);
      *reinterpret_cast<uintx4*>(ht16 + e) = o;
    }
  } else {
    // ET transpose: 32 blocks, 32 k-rows each, coalesced emb reads.
    const int k0 = (bid - BB) * 32;
    #pragma unroll
    for (int u = 0; u < 4; ++u) {
      int e = u * 1024 + t * 4;
      int r = e >> 7, c = e & 127;
      float4 z = {0.f, 0.f, 0.f, 0.f};
      float4 v = (k0 + r < AA)
          ? *reinterpret_cast<const float4*>(emb + (size_t)(k0 + r) * DD + c) : z;
      float* d = &hsf[r * 129 + c];
      d[0] = v.x; d[1] = v.y; d[2] = v.z; d[3] = v.w;
    }
    __syncthreads();
    int c = t >> 1, j0 = (t & 1) * 16;
    float x[16];
    #pragma unroll
    for (int j = 0; j < 16; ++j) x[j] = hsf[(j0 + j) * 129 + c];
    uintx4 o0, o1;
    o0.x = packbf_rne(x[0], x[1]);  o0.y = packbf_rne(x[2], x[3]);
    o0.z = packbf_rne(x[4], x[5]);  o0.w = packbf_rne(x[6], x[7]);
    o1.x = packbf_rne(x[8], x[9]);  o1.y = packbf_rne(x[10], x[11]);
    o1.z = packbf_rne(x[12], x[13]); o1.w = packbf_rne(x[14], x[15]);
    unsigned short* dst = ET + (size_t)c * KPAD + k0 + j0;
    *reinterpret_cast<uintx4*>(dst) = o0;
    *reinterpret_cast<uintx4*>(dst + 8) = o1;
  }
}

// ---------------------------------------------------------------------------
// Fused kernel, grid = 512 (exactly 2 blocks/CU at 68 KB LDS, zero tail):
// EVERY block does one 16-row attn tile AND one 16-row attr-GEMM tile.
// Parity (wid&1) flips the order so ~half the machine streams Aattr from HBM
// while the other half does the L2/LDS-bound attn phases.
// LDS-As QK structure preserved verbatim: As built ONCE with full 256-thread
// parallelism, QK inner loop is pure ds_read_b128 + MFMA (register-As
// variants of R6..R9 all regressed on that chain).
// ---------------------------------------------------------------------------
struct AttnSmem {
  __align__(16) unsigned short Hs[NN * 128];        // 32768 B bf16 h (swizzled)
  union {
    __align__(16) unsigned short As[4 * 16 * 256];  // 32768 B (QK phase only)
    struct {
      __align__(16) float Sa[16 * 129];             // 8256 B (post-QK)
      __align__(16) unsigned short W[16 * 128];     // 4096 B (softmax out)
    } sw;
  } u2;
  __align__(16) float saf[4 * 256];                 // 4096 B scale table
};  // 69632 B

#define BK 64
struct AttrSmem {
  __align__(16) unsigned short ETs[2][DD * BK];     // 32768 B
  __align__(16) unsigned short As2[2][16 * BK];     // 4096 B (16-row tile)
};  // 36864 B

union FusedSmem { AttnSmem a; AttrSmem g; };        // 69632 B

__device__ __forceinline__ void attn_body(
    AttnSmem& s, const float* __restrict__ hidden,
    const int* __restrict__ adj, const float* __restrict__ amat,
    const unsigned short* __restrict__ HTg, float* __restrict__ out0,
    int wid)
{
  const int t = threadIdx.x;
  const int L = t & 63, w = t >> 6;     // wave w = j-quarter / d-quarter
  const int lr = L & 15, lq = L >> 4;   // MFMA lane coords
  const int b = wid >> 3;
  const int i0 = (wid & 7) * 16;

  // ---- prefetch adj (in flight under staging) ----
  const int* adjb = adj + ((size_t)b * NN + i0) * NN;
  int adjv[8];
  #pragma unroll
  for (int nt = 0; nt < 2; ++nt)
    #pragma unroll
    for (int r = 0; r < 4; ++r)
      adjv[nt * 4 + r] = adjb[(lq * 4 + r) * NN + w * 32 + nt * 16 + lr];

  // ---- stage Hs from fp32 hidden (convert in flight; swizzle c^(row&15)) ----
  const float* hb = hidden + (size_t)b * NN * DD;
  #pragma unroll
  for (int u = 0; u < 8; ++u) {
    int id = u * 256 + t;
    int r = id >> 4, c = id & 15;
    const float* src = hb + r * 128 + c * 8;
    float4 v0 = *reinterpret_cast<const float4*>(src);
    float4 v1 = *reinterpret_cast<const float4*>(src + 4);
    uintx4 o;
    o.x = packbf_rne(v0.x, v0.y); o.y = packbf_rne(v0.z, v0.w);
    o.z = packbf_rne(v1.x, v1.y); o.w = packbf_rne(v1.z, v1.w);
    *reinterpret_cast<uintx4*>(&s.Hs[r * 128 + ((c ^ (r & 15)) << 3)]) = o;
  }
  // ---- scale table: saf[k][d]=0.6*a[d][k], saf[k][128+d]=0.4*a[d][k] ----
  {
    float v1 = amat[t], v2 = amat[t + 256];
    int dI = t >> 2, k = t & 3;
    s.saf[k * 256 + dI] = 0.6f * v1;
    s.saf[k * 256 + 128 + dI] = 0.4f * v1;
    s.saf[k * 256 + 64 + dI] = 0.6f * v2;
    s.saf[k * 256 + 192 + dI] = 0.4f * v2;
  }
  __syncthreads();

  // ---- build As[k][i][d'] (d'<128: h*0.6a_k ; d'>=128: |h|*0.4a_k) ----
  #pragma unroll
  for (int u = 0; u < 8; ++u) {
    int id = u * 256 + t;
    int k = id >> 9, ii = (id >> 5) & 15, c = id & 31;
    int srow = i0 + ii;
    int dchunk = c & 15;
    uintx4 hv = *reinterpret_cast<const uintx4*>(
        &s.Hs[srow * 128 + ((dchunk ^ (srow & 15)) << 3)]);
    if (c & 16) {
      hv.x &= 0x7fff7fffu; hv.y &= 0x7fff7fffu;
      hv.z &= 0x7fff7fffu; hv.w &= 0x7fff7fffu;
    }
    const float* sf = &s.saf[k * 256 + c * 8];
    uintx4 o;
    o.x = packbf(bflo(hv.x) * sf[0], bfhi(hv.x) * sf[1]);
    o.y = packbf(bflo(hv.y) * sf[2], bfhi(hv.y) * sf[3]);
    o.z = packbf(bflo(hv.z) * sf[4], bfhi(hv.z) * sf[5]);
    o.w = packbf(bflo(hv.w) * sf[6], bfhi(hv.w) * sf[7]);
    *reinterpret_cast<uintx4*>(&s.u2.As[k * 4096 + ii * 256 + ((c ^ ii) << 3)]) = o;
  }
  __syncthreads();

  // ---- QK: all 4 edge-type scores in one K'=256 GEMM, 8 MFMA/step ----
  floatx4 acc[4][2];
  #pragma unroll
  for (int k = 0; k < 4; ++k)
    #pragma unroll
    for (int nt = 0; nt < 2; ++nt) acc[k][nt] = floatx4{0.f, 0.f, 0.f, 0.f};

  #pragma unroll
  for (int kt = 0; kt < 8; ++kt) {
    int ca = lq + 4 * kt;
    short8 afr[4];
    #pragma unroll
    for (int k = 0; k < 4; ++k)
      afr[k] = *reinterpret_cast<const short8*>(
          &s.u2.As[k * 4096 + lr * 256 + ((ca ^ lr) << 3)]);
    int cb = lq + 4 * (kt & 3);
    short8 bfr[2];
    #pragma unroll
    for (int nt = 0; nt < 2; ++nt) {
      int jrow = w * 32 + nt * 16 + lr;
      uintx4 hv = *reinterpret_cast<const uintx4*>(
          &s.Hs[jrow * 128 + ((cb ^ (jrow & 15)) << 3)]);
      if (kt >= 4) {
        hv.x &= 0x7fff7fffu; hv.y &= 0x7fff7fffu;
        hv.z &= 0x7fff7fffu; hv.w &= 0x7fff7fffu;
      }
      bfr[nt] = u2s(hv);
    }
    #pragma unroll
    for (int k = 0; k < 4; ++k)
      #pragma unroll
      for (int nt = 0; nt < 2; ++nt)
        acc[k][nt] = __builtin_amdgcn_mfma_f32_16x16x32_bf16(
            afr[k], bfr[nt], acc[k][nt], 0, 0, 0);
  }
  __syncthreads();  // all As reads done; Sa/W may now overlay As

  // ---- prefetch PV B-frags from HTg (hides under selection/softmax) ----
  short8 pvb[2][4];
  const unsigned short* ht = HTg + (size_t)b * NN * DD;
  #pragma unroll
  for (int nt = 0; nt < 2; ++nt)
    #pragma unroll
    for (int kt = 0; kt < 4; ++kt) {
      int dI = w * 32 + nt * 16 + lr;
      pvb[nt][kt] = *reinterpret_cast<const short8*>(ht + dI * 128 + kt * 32 + lq * 8);
    }

  // ---- in-register adj selection; C/D: col=lane&15, row=(lane>>4)*4+reg ----
  #pragma unroll
  for (int nt = 0; nt < 2; ++nt)
    #pragma unroll
    for (int r = 0; r < 4; ++r) {
      int ii = lq * 4 + r;
      int j = w * 32 + nt * 16 + lr;
      int ad = adjv[nt * 4 + r];
      float al = NEG_INF;
      al = (ad == 1) ? acc[0][nt][r] : al;
      al = (ad == 2) ? acc[1][nt][r] : al;
      al = (ad == 3) ? acc[2][nt][r] : al;
      al = (ad == 4) ? acc[3][nt][r] : al;
      s.u2.sw.Sa[ii * 129 + j] = al;
    }
  __syncthreads();

  // ---- softmax: one full row per wave (lane holds j=L and j=L+64) ----
  #pragma unroll
  for (int p = 0; p < 4; ++p) {
    int ii = w * 4 + p;
    float a1 = s.u2.sw.Sa[ii * 129 + L];
    float a2 = s.u2.sw.Sa[ii * 129 + 64 + L];
    float m = fmaxf(a1, a2);
    #pragma unroll
    for (int off = 32; off > 0; off >>= 1) m = fmaxf(m, __shfl_xor(m, off, 64));
    // all-masked row: a-m==0 -> uniform (matches jax); clamp guards exp
    float e1 = __expf(fmaxf(a1 - m, -80.f));
    float e2 = __expf(fmaxf(a2 - m, -80.f));
    float ss = e1 + e2;
    #pragma unroll
    for (int off = 32; off > 0; off >>= 1) ss += __shfl_xor(ss, off, 64);
    float inv = 1.f / ss;
    int j2 = L + 64;
    s.u2.sw.W[ii * 128 + (((L >> 3) ^ ii) << 3) + (L & 7)] = bf_rne(e1 * inv);
    s.u2.sw.W[ii * 128 + (((j2 >> 3) ^ ii) << 3) + (j2 & 7)] = bf_rne(e2 * inv);
  }
  __syncthreads();

  // ---- PV: out[i][d] = sum_j W[i,j] * h[j,d] (B from HTg prefetch) ----
  floatx4 oacc[2];
  oacc[0] = floatx4{0.f, 0.f, 0.f, 0.f};
  oacc[1] = floatx4{0.f, 0.f, 0.f, 0.f};
  #pragma unroll
  for (int kt = 0; kt < 4; ++kt) {
    int c = lq + 4 * kt;
    short8 wf = *reinterpret_cast<const short8*>(
        &s.u2.sw.W[lr * 128 + ((c ^ lr) << 3)]);
    #pragma unroll
    for (int nt = 0; nt < 2; ++nt)
      oacc[nt] = __builtin_amdgcn_mfma_f32_16x16x32_bf16(
          wf, pvb[nt][kt], oacc[nt], 0, 0, 0);
  }
  float* ob = out0 + ((size_t)b * NN + i0) * DD;
  #pragma unroll
  for (int nt = 0; nt < 2; ++nt)
    #pragma unroll
    for (int r = 0; r < 4; ++r)
      ob[(lq * 4 + r) * DD + w * 32 + nt * 16 + lr] = oacc[nt][r];
}

// 16-row attr tile, 2-deep register prefetch (named sets A/B — no runtime-
// indexed ext_vector arrays, which would spill to scratch).
__device__ __forceinline__ void attr_body(
    AttrSmem& s, const float* __restrict__ Aattr,
    const unsigned short* __restrict__ ET, float* __restrict__ out1,
    int wid)
{
  const int t = threadIdx.x;
  const int L = t & 63, w = t >> 6;
  const int lr = L & 15, lq = L >> 4;
  const int r0 = wid * 16;

  const int ar = t >> 4;          // A row 0..15 (16 threads per row)
  const int ak = (t & 15) * 4;    // k offset within BK (float4 granularity)
  const int ec = t >> 1, ej0 = (t & 1) * 4;
  const float* arow = Aattr + (size_t)(r0 + ar) * AA;
  const unsigned short* erow = ET + (size_t)ec * KPAD;

  float4 paA, paB;
  uintx4 peA[4], peB[4];

#define ATTR_FETCH(PA, PE, IT) do {                                          \
    int kb = (IT) * BK; int k4 = kb + ak;                                    \
    float4 z = {0.f, 0.f, 0.f, 0.f};                                        \
    PA = (k4 < AA) ? *reinterpret_cast<const float4*>(arow + k4) : z;        \
    _Pragma("unroll")                                                        \
    for (int q = 0; q < 4; ++q)                                              \
      PE[q] = *reinterpret_cast<const uintx4*>(erow + kb + (ej0 + q) * 8);   \
  } while (0)

#define ATTR_STAGE(PA, PE, BUF) do {                                         \
    uintx2 o; o.x = packbf(PA.x, PA.y); o.y = packbf(PA.z, PA.w);            \
    int cidx = ak >> 3, half = ak & 7;                                       \
    *reinterpret_cast<uintx2*>(                                              \
        &s.As2[BUF][ar * BK + ((cidx ^ (ar & 7)) << 3) + half]) = o;         \
    _Pragma("unroll")                                                        \
    for (int q = 0; q < 4; ++q)                                              \
      *reinterpret_cast<uintx4*>(                                            \
          &s.ETs[BUF][ec * BK + (((ej0 + q) ^ (ec & 7)) << 3)]) = PE[q];     \
  } while (0)

#define ATTR_COMPUTE(BUF) do {                                               \
    _Pragma("unroll")                                                        \
    for (int ks = 0; ks < 2; ++ks) {                                         \
      int c = lq + 4 * ks;                                                   \
      short8 af = *reinterpret_cast<const short8*>(                          \
          &s.As2[BUF][lr * BK + ((c ^ (lr & 7)) << 3)]);                     \
      _Pragma("unroll")                                                      \
      for (int nt = 0; nt < 2; ++nt) {                                       \
        int n = w * 32 + nt * 16 + lr;                                       \
        short8 bf = *reinterpret_cast<const short8*>(                        \
            &s.ETs[BUF][n * BK + ((c ^ (n & 7)) << 3)]);                     \
        acc[nt] = __builtin_amdgcn_mfma_f32_16x16x32_bf16(                   \
            af, bf, acc[nt], 0, 0, 0);                                       \
      }                                                                      \
    }                                                                        \
  } while (0)

  floatx4 acc[2];
  acc[0] = floatx4{0.f, 0.f, 0.f, 0.f};
  acc[1] = floatx4{0.f, 0.f, 0.f, 0.f};

  ATTR_FETCH(paA, peA, 0);
  ATTR_FETCH(paB, peB, 1);
  for (int ith = 0; ith < 8; ++ith) {
    // Safe: a thread reaches STAGE(buf) only after the barrier that proves
    // every thread finished the previous COMPUTE on that buffer.
    ATTR_STAGE(paA, peA, 0);
    __syncthreads();
    if (ith < 7) ATTR_FETCH(paA, peA, 2 * ith + 2);  // lands ~2 iters later
    ATTR_COMPUTE(0);
    ATTR_STAGE(paB, peB, 1);
    __syncthreads();
    if (ith < 7) ATTR_FETCH(paB, peB, 2 * ith + 3);
    ATTR_COMPUTE(1);
  }
#undef ATTR_FETCH
#undef ATTR_STAGE
#undef ATTR_COMPUTE

  float* ob = out1 + (size_t)r0 * DD;
  #pragma unroll
  for (int nt = 0; nt < 2; ++nt)
    #pragma unroll
    for (int r = 0; r < 4; ++r)
      ob[(lq * 4 + r) * DD + w * 32 + nt * 16 + lr] = acc[nt][r];
}

__global__ __launch_bounds__(256, 2) void fused_kernel(
    const float* __restrict__ hidden, const int* __restrict__ adj,
    const float* __restrict__ amat, const float* __restrict__ Aattr,
    const unsigned short* __restrict__ ET, const unsigned short* __restrict__ HTg,
    float* __restrict__ out0, float* __restrict__ out1)
{
  __shared__ FusedSmem sm;
  // XCD-chunked swizzle (512 % 8 == 0 -> bijective): the 8 blocks sharing a
  // batch b land on one XCD's L2 (hidden[b] 64 KB + HTg[b] 32 KB resident).
  const int bid = blockIdx.x;
  const int wid = (bid & 7) * 64 + (bid >> 3);
  if (wid & 1) {
    attn_body(sm.a, hidden, adj, amat, HTg, out0, wid);
    __syncthreads();  // LDS union handoff (skewed waves)
    attr_body(sm.g, Aattr, ET, out1, wid);
  } else {
    attr_body(sm.g, Aattr, ET, out1, wid);
    __syncthreads();
    attn_body(sm.a, hidden, adj, amat, HTg, out0, wid);
  }
}

extern "C" void kernel_launch(void* const* d_in, const int* in_sizes, int n_in,
                              void* d_out, int out_size, void* d_ws, size_t ws_size,
                              hipStream_t stream) {
  const float* hidden = (const float*)d_in[0];  // [64,128,128] fp32
  const int*   adj    = (const int*)d_in[1];    // [64,128,128] int32
  const float* amat   = (const float*)d_in[2];  // [128,4] fp32
  const float* Aattr  = (const float*)d_in[3];  // [64,128,1000] fp32
  const float* emb    = (const float*)d_in[4];  // [1000,128] fp32

  float* out0 = (float*)d_out;                  // output    [64,128,128] fp32
  float* out1 = out0 + (size_t)BB * NN * DD;    // attr_sess [64,128,128] fp32

  // d_ws layout (rebuilt every call): bf16 operand copies
  unsigned short* ET  = (unsigned short*)d_ws;      // [128][1024]
  unsigned short* HTg = ET + (size_t)DD * KPAD;     // [64][128][128] h^T

  prep_kernel<<<BB + 32, 256, 0, stream>>>(hidden, emb, ET, HTg);
  fused_kernel<<<512, 256, 0, stream>>>(hidden, adj, amat, Aattr, ET, HTg,
                                        out0, out1);
}